// Round 1
// baseline (2638.091 us; speedup 1.0000x reference)
//
#include <hip/hip_runtime.h>
#include <hip/hip_bf16.h>
#include <cfloat>
#include <cmath>

typedef float f32x4 __attribute__((ext_vector_type(4)));
typedef float f32x2 __attribute__((ext_vector_type(2)));
typedef short bf16x8 __attribute__((ext_vector_type(8)));

#define HID 102
#define KEEPN 39
#define DIMD 512

static __device__ __forceinline__ unsigned int f2bf(float v) {
  unsigned int b = __float_as_uint(v);
  return (b + 0x7FFFu + ((b >> 16) & 1u)) >> 16;  // RNE bf16
}
static __device__ __forceinline__ float wsum(float v) {
#pragma unroll
  for (int m = 1; m < 64; m <<= 1) v += __shfl_xor(v, m, 64);
  return v;
}
static __device__ __forceinline__ float wmaxr(float v) {
#pragma unroll
  for (int m = 1; m < 64; m <<= 1) v = fmaxf(v, __shfl_xor(v, m, 64));
  return v;
}
static __device__ __forceinline__ float bsum(float v, float* red4, int lane, int wid) {
  v = wsum(v);
  if (lane == 0) red4[wid] = v;
  __syncthreads();
  float r = red4[0] + red4[1] + red4[2] + red4[3];
  __syncthreads();
  return r;
}

// ---------------- K0: fold ln_g/ln_b into W1, transpose weights ----------------
__global__ __launch_bounds__(256) void k0_prep(
    const float* __restrict__ W1, const float* __restrict__ b1,
    const float* __restrict__ W2, const float* __restrict__ lng,
    const float* __restrict__ lnb,
    float* __restrict__ w1gT, float* __restrict__ b1eff, float* __restrict__ w2T) {
  int tid = blockIdx.x * 256 + threadIdx.x;
  // w1gT[c][k] = lng[k]*W1[k][c]   (102 x 512)
  for (int idx = tid; idx < HID * DIMD; idx += (int)gridDim.x * 256) {
    int c = idx >> 9, k = idx & 511;
    w1gT[idx] = lng[k] * W1[k * HID + c];
  }
  // w2T[l][k] (stride 104), zero-padded cols 102..103
  for (int idx = tid; idx < KEEPN * 104; idx += (int)gridDim.x * 256) {
    int l = idx / 104, k = idx - l * 104;
    w2T[idx] = (k < HID) ? W2[k * KEEPN + l] : 0.0f;
  }
  // b1eff[c] = b1[c] + sum_k lnb[k]*W1[k][c]
  if (blockIdx.x == 0 && threadIdx.x < 104) {
    int c = threadIdx.x;
    float s = 0.f;
    if (c < HID) {
      s = b1[c];
      for (int k = 0; k < DIMD; ++k) s += lnb[k] * W1[k * HID + c];
    }
    b1eff[c] = s;
  }
}

// ---------------- K1a: per image: LN -> H1(gelu) -> W2 -> wmat (pre-softmax, scaled) ----------------
__global__ __launch_bounds__(256) void k1a(
    const float* __restrict__ img, const float* __restrict__ w1gT,
    const float* __restrict__ b1eff, const float* __restrict__ w2T,
    const float* __restrict__ b2, const float* __restrict__ scale,
    float* __restrict__ wmat) {
  int b = blockIdx.x;
  int tid = threadIdx.x;
  int lane = tid & 63, wid = tid >> 6;
  __shared__ float mu_s[196], rs_s[196];
  __shared__ __attribute__((aligned(16))) float w2t_s[KEEPN * 104];
  __shared__ float b1e_s[104];
  __shared__ __attribute__((aligned(16))) float uni[6864];
  float* x_s = uni;            // [32][68] transposed xn chunk
  float* w1g_s = uni + 2176;   // [104][36] w1gT chunk
  float* h1_s = uni;           // [104][66] hidden (union; phases are barrier-separated)
  const float* xb = img + (size_t)b * 197 * DIMD + DIMD;  // spatial rows
  float scv = scale[0];
  for (int u = tid; u < KEEPN * 104 / 4; u += 256)
    ((f32x4*)w2t_s)[u] = ((const f32x4*)w2T)[u];
  if (tid < 104) b1e_s[tid] = b1eff[tid];
  // phase A: LN stats, one token per wave
  for (int it = 0; it < 49; ++it) {
    int t = it * 4 + wid;
    const float* xr = xb + (size_t)t * DIMD + lane * 8;
    f32x4 v0 = *(const f32x4*)xr;
    f32x4 v1 = *(const f32x4*)(xr + 4);
    float s = v0[0]+v0[1]+v0[2]+v0[3]+v1[0]+v1[1]+v1[2]+v1[3];
    float q = v0[0]*v0[0]+v0[1]*v0[1]+v0[2]*v0[2]+v0[3]*v0[3]
            + v1[0]*v1[0]+v1[1]*v1[1]+v1[2]*v1[2]+v1[3]*v1[3];
    s = wsum(s); q = wsum(q);
    if (lane == 0) {
      float mu = s * (1.f/512.f);
      float var = q * (1.f/512.f) - mu*mu;
      mu_s[t] = mu;
      rs_s[t] = 1.f / sqrtf(var + 1e-5f);
    }
  }
  __syncthreads();
  int kh = tid >> 7, r = tid & 127, tg = r & 15, cg = r >> 4;
  for (int t0 = 0; t0 < 196; t0 += 64) {
    float acc[4][13] = {};
    for (int kc = 0; kc < DIMD; kc += 32) {
      __syncthreads();
#pragma unroll
      for (int j = 0; j < 2; ++j) {           // stage xn transposed [kk][tt]
        int u = tid + 256 * j;
        int tt = u >> 3, f = u & 7;
        int t = t0 + tt;
        if (t < 196) {
          f32x4 v = *(const f32x4*)(xb + (size_t)t * DIMD + kc + 4*f);
          float mu = mu_s[t], rs = rs_s[t];
          x_s[(4*f+0)*68 + tt] = (v[0]-mu)*rs;
          x_s[(4*f+1)*68 + tt] = (v[1]-mu)*rs;
          x_s[(4*f+2)*68 + tt] = (v[2]-mu)*rs;
          x_s[(4*f+3)*68 + tt] = (v[3]-mu)*rs;
        }
      }
#pragma unroll
      for (int j = 0; j < 4; ++j) {           // stage w1gT chunk [c][kk]
        int u = tid + 256 * j;
        if (u < 816) {
          int c = u >> 3, f = u & 7;
          *(f32x4*)&w1g_s[c*36 + 4*f] = *(const f32x4*)(w1gT + c*DIMD + kc + 4*f);
        }
      }
      __syncthreads();
#pragma unroll
      for (int k4 = 0; k4 < 4; ++k4) {
        int kk = kh*16 + k4*4;
        f32x4 a0 = *(const f32x4*)&x_s[(kk+0)*68 + 4*tg];
        f32x4 a1 = *(const f32x4*)&x_s[(kk+1)*68 + 4*tg];
        f32x4 a2 = *(const f32x4*)&x_s[(kk+2)*68 + 4*tg];
        f32x4 a3 = *(const f32x4*)&x_s[(kk+3)*68 + 4*tg];
#pragma unroll
        for (int ci = 0; ci < 13; ++ci) {
          f32x4 w = *(const f32x4*)&w1g_s[(cg*13+ci)*36 + kk];
#pragma unroll
          for (int t = 0; t < 4; ++t)
            acc[t][ci] += a0[t]*w[0] + a1[t]*w[1] + a2[t]*w[2] + a3[t]*w[3];
        }
      }
    }
    __syncthreads();
    if (kh == 1) {                            // write k-half partials
#pragma unroll
      for (int ci = 0; ci < 13; ++ci) {
        int c = cg*13 + ci;
        if (c < HID)
#pragma unroll
          for (int t = 0; t < 4; ++t) h1_s[c*66 + 4*tg + t] = acc[t][ci];
      }
    }
    __syncthreads();
    if (kh == 0) {                            // combine + bias + exact gelu
#pragma unroll
      for (int ci = 0; ci < 13; ++ci) {
        int c = cg*13 + ci;
        if (c < HID)
#pragma unroll
          for (int t = 0; t < 4; ++t) {
            float v = h1_s[c*66 + 4*tg + t] + acc[t][ci] + b1e_s[c];
            v = 0.5f * v * (1.f + erff(v * 0.70710678118654752f));
            h1_s[c*66 + 4*tg + t] = v;
          }
      }
    }
    if (tid < 128) h1_s[(HID + (tid >> 6))*66 + (tid & 63)] = 0.f; // zero pad rows
    __syncthreads();
    {                                          // W2 mini-GEMM
      int t4 = tid & 31, lg = tid >> 5;
      int nl = (lg == 7) ? 4 : 5;
      float a2c[2][5] = {};
      for (int k = 0; k < 104; k += 4) {
        f32x4 wvv[5];
#pragma unroll
        for (int li = 0; li < 5; ++li) {
          if (li < nl) wvv[li] = *(const f32x4*)&w2t_s[(lg*5+li)*104 + k];
          else wvv[li] = (f32x4){0.f,0.f,0.f,0.f};
        }
#pragma unroll
        for (int j = 0; j < 4; ++j) {
          f32x2 h = *(const f32x2*)&h1_s[(k+j)*66 + 2*t4];
#pragma unroll
          for (int li = 0; li < 5; ++li) {
            a2c[0][li] += h[0]*wvv[li][j];
            a2c[1][li] += h[1]*wvv[li][j];
          }
        }
      }
#pragma unroll
      for (int li = 0; li < 5; ++li) {
        if (li < nl) {
          int l = lg*5 + li;
          float bb = b2[l];
#pragma unroll
          for (int tp = 0; tp < 2; ++tp) {
            int t = t0 + 2*t4 + tp;
            if (t < 196) wmat[((size_t)b*KEEPN + l)*196 + t] = (a2c[tp][li] + bb) * scv;
          }
        }
      }
    }
  }
}

// ---------------- K1agg: per image: softmax over t + aggr + norms + mean ----------------
__global__ __launch_bounds__(256) void k1agg(
    const float* __restrict__ img, const float* __restrict__ wmat,
    float* __restrict__ agn, unsigned short* __restrict__ agn_bf,
    float* __restrict__ na_g, float* __restrict__ gloraw) {
  int b = blockIdx.x, tid = threadIdx.x;
  int lane = tid & 63, wid = tid >> 6;
  __shared__ __attribute__((aligned(16))) float wm_s[KEEPN * 200];
  __shared__ float red_s[13 * 4];
  __shared__ float na_s[13];
  for (int u = tid; u < KEEPN * 49; u += 256) {
    int l = u / 49, t4 = u - l * 49;
    *(f32x4*)&wm_s[l*200 + 4*t4] = *(const f32x4*)(wmat + ((size_t)b*KEEPN + l)*196 + 4*t4);
  }
  __syncthreads();
  for (int l = wid; l < KEEPN; l += 4) {       // softmax over 196, one row per wave
    float v0 = wm_s[l*200 + lane];
    float v1 = wm_s[l*200 + 64 + lane];
    float v2 = wm_s[l*200 + 128 + lane];
    float v3 = (lane < 4) ? wm_s[l*200 + 192 + lane] : -FLT_MAX;
    float mx = wmaxr(fmaxf(fmaxf(v0, v1), fmaxf(v2, v3)));
    float e0 = expf(v0 - mx), e1 = expf(v1 - mx), e2 = expf(v2 - mx);
    float e3 = (lane < 4) ? expf(v3 - mx) : 0.f;
    float s = wsum(e0 + e1 + e2 + e3);
    float inv = 1.f / s;
    wm_s[l*200 + lane] = e0 * inv;
    wm_s[l*200 + 64 + lane] = e1 * inv;
    wm_s[l*200 + 128 + lane] = e2 * inv;
    if (lane < 4) wm_s[l*200 + 192 + lane] = e3 * inv;
  }
  __syncthreads();
  const float* xb = img + (size_t)b * 197 * DIMD + DIMD;
  int c0 = tid, c1 = tid + 256;
  float ms0 = 0.f, ms1 = 0.f;
  for (int lp = 0; lp < 3; ++lp) {
    int l0 = lp * 13;
    float a0[13] = {}, a1[13] = {};
    for (int t4 = 0; t4 < 49; ++t4) {
      float xx0[4], xx1[4];
#pragma unroll
      for (int j = 0; j < 4; ++j) {
        int t = 4*t4 + j;
        xx0[j] = xb[(size_t)t*DIMD + c0];
        xx1[j] = xb[(size_t)t*DIMD + c1];
      }
#pragma unroll
      for (int li = 0; li < 13; ++li) {
        f32x4 w = *(const f32x4*)&wm_s[(l0+li)*200 + 4*t4];
#pragma unroll
        for (int j = 0; j < 4; ++j) {
          a0[li] += w[j]*xx0[j];
          a1[li] += w[j]*xx1[j];
        }
      }
    }
#pragma unroll
    for (int li = 0; li < 13; ++li) {
      float p = wsum(a0[li]*a0[li] + a1[li]*a1[li]);
      if (lane == 0) red_s[li*4 + wid] = p;
    }
    __syncthreads();
    if (tid < 13) {
      float s = red_s[tid*4] + red_s[tid*4+1] + red_s[tid*4+2] + red_s[tid*4+3];
      float n = sqrtf(s);
      na_s[tid] = n;
      na_g[b*KEEPN + l0 + tid] = n;
    }
    __syncthreads();
#pragma unroll
    for (int li = 0; li < 13; ++li) {
      int l = l0 + li;
      float inv = 1.f / fmaxf(na_s[li], 1e-12f);
      size_t base = ((size_t)b*KEEPN + l) * DIMD;
      float v0 = a0[li]*inv, v1 = a1[li]*inv;
      agn[base + c0] = v0; agn[base + c1] = v1;
      agn_bf[base + c0] = (unsigned short)f2bf(v0);
      agn_bf[base + c1] = (unsigned short)f2bf(v1);
      ms0 += a0[li]; ms1 += a1[li];
    }
    __syncthreads();
  }
  gloraw[(size_t)b*DIMD + c0] = ms0;
  gloraw[(size_t)b*DIMD + c1] = ms1;
}

// ---------------- K1b: per image: glo, cls_norm, att_self, Gram ----------------
__global__ __launch_bounds__(256) void k1b(
    const float* __restrict__ img, const float* __restrict__ gloraw,
    const float* __restrict__ agn, const float* __restrict__ na_g,
    unsigned short* __restrict__ clsn_bf, float* __restrict__ attSelf,
    float* __restrict__ G) {
  int b = blockIdx.x, tid = threadIdx.x;
  int lane = tid & 63, wid = tid >> 6;
  __shared__ float glo_s[DIMD];
  __shared__ float red4[4];
  int c0 = tid, c1 = tid + 256;
  float m0 = gloraw[(size_t)b*DIMD + c0] * (1.f/39.f);
  float m1 = gloraw[(size_t)b*DIMD + c1] * (1.f/39.f);
  float nt = bsum(m0*m0 + m1*m1, red4, lane, wid);
  float inv = 1.f / fmaxf(sqrtf(nt), 1e-12f);
  glo_s[c0] = m0*inv; glo_s[c1] = m1*inv;
  const float* cls = img + (size_t)b * 197 * DIMD;
  float x0 = cls[c0], x1 = cls[c1];
  float n2 = bsum(x0*x0 + x1*x1, red4, lane, wid);
  float inv2 = 1.f / fmaxf(sqrtf(n2), 1e-12f);
  clsn_bf[(size_t)b*DIMD + c0] = (unsigned short)f2bf(x0*inv2);
  clsn_bf[(size_t)b*DIMD + c1] = (unsigned short)f2bf(x1*inv2);
  __syncthreads();
  for (int l = 0; l < KEEPN; ++l) {
    const float* ar = agn + ((size_t)b*KEEPN + l)*DIMD;
    float p = glo_s[c0]*ar[c0] + glo_s[c1]*ar[c1];
    float s = bsum(p, red4, lane, wid);
    if (tid == 0) attSelf[b*KEEPN + l] = s;
  }
  for (int p = tid; p < KEEPN*KEEPN; p += 256) {
    int l = p / KEEPN, lq = p - l*KEEPN;
    const float* A = agn + ((size_t)b*KEEPN + l)*DIMD;
    const float* B = agn + ((size_t)b*KEEPN + lq)*DIMD;
    float d = 0.f;
    for (int c = 0; c < DIMD; c += 4) {
      f32x4 va = *(const f32x4*)(A + c);
      f32x4 vb = *(const f32x4*)(B + c);
      d += va[0]*vb[0] + va[1]*vb[1] + va[2]*vb[2] + va[3]*vb[3];
    }
    G[(size_t)b*(KEEPN*KEEPN) + p] = d * na_g[b*KEEPN + l] * na_g[b*KEEPN + lq];
  }
}

// ---------------- K2: per caption: word norms (bf16) + cap_glo ----------------
__global__ __launch_bounds__(256) void k2(
    const float* __restrict__ cap, const int* __restrict__ lens,
    unsigned short* __restrict__ capn_bf, float* __restrict__ cglo) {
  int i = blockIdx.x, tid = threadIdx.x;
  int lane = tid & 63, wid = tid >> 6;
  __shared__ float red4[4];
  int len = lens[i];
  float nwf = (float)len;
  const float* cb = cap + (size_t)i * 64 * DIMD;
  for (int w = wid; w < 64; w += 4) {
    const float* xr = cb + (size_t)w*DIMD + lane*8;
    f32x4 v0 = *(const f32x4*)xr;
    f32x4 v1 = *(const f32x4*)(xr + 4);
    float q = v0[0]*v0[0]+v0[1]*v0[1]+v0[2]*v0[2]+v0[3]*v0[3]
            + v1[0]*v1[0]+v1[1]*v1[1]+v1[2]*v1[2]+v1[3]*v1[3];
    q = wsum(q);
    float inv = 1.f / fmaxf(sqrtf(q), 1e-12f);
    uint4 o;
    o.x = f2bf(v0[0]*inv) | (f2bf(v0[1]*inv) << 16);
    o.y = f2bf(v0[2]*inv) | (f2bf(v0[3]*inv) << 16);
    o.z = f2bf(v1[0]*inv) | (f2bf(v1[1]*inv) << 16);
    o.w = f2bf(v1[2]*inv) | (f2bf(v1[3]*inv) << 16);
    *(uint4*)(capn_bf + ((size_t)i*64 + w)*DIMD + lane*8) = o;
  }
  int c0 = tid, c1 = tid + 256;
  float s0 = 0.f, s1 = 0.f;
  for (int w = 0; w < len; ++w) {
    s0 += cb[(size_t)w*DIMD + c0];
    s1 += cb[(size_t)w*DIMD + c1];
  }
  s0 /= nwf; s1 /= nwf;
  float nt = bsum(s0*s0 + s1*s1, red4, lane, wid);
  float inv = 1.f / fmaxf(sqrtf(nt), 1e-12f);
  cglo[(size_t)i*DIMD + c0] = s0*inv;
  cglo[(size_t)i*DIMD + c1] = s1*inv;
}

// ---------------- K3: per (image b, caption i) pair ----------------
__global__ __launch_bounds__(256) void k3(
    const unsigned short* __restrict__ capn_bf, const unsigned short* __restrict__ agn_bf,
    const unsigned short* __restrict__ clsn_bf, const float* __restrict__ agn,
    const float* __restrict__ cglo, const float* __restrict__ na_g,
    const float* __restrict__ attSelf, const float* __restrict__ G,
    const int* __restrict__ lens, float* __restrict__ out) {
  int b = blockIdx.x, i = blockIdx.y;
  int tid = threadIdx.x, lane = tid & 63, wv = tid >> 6;
  __shared__ __attribute__((aligned(16))) unsigned short ca_s[64 * 64];  // capn chunk, k8-XOR swizzled
  __shared__ __attribute__((aligned(16))) unsigned short ag_s[48 * 64];  // agn(39)+cls(1)+zeros chunk
  __shared__ float d2_s[64 * 42];
  __shared__ float atty_s[KEEPN];
  __shared__ float wdna_s[KEEPN];
  __shared__ float sel_s[KEEPN];
  __shared__ float nex_s;
  __shared__ float part_s[4];
  int len = lens[i];
  f32x4 acc0 = {0.f,0.f,0.f,0.f}, acc1 = {0.f,0.f,0.f,0.f}, acc2v = {0.f,0.f,0.f,0.f};
  float attv = 0.f;
  int al = tid >> 2, ap = tid & 3;
  const unsigned short* cb  = capn_bf + (size_t)i * 64 * DIMD;
  const unsigned short* ab  = agn_bf + (size_t)b * KEEPN * DIMD;
  const unsigned short* clb = clsn_bf + (size_t)b * DIMD;
  for (int kc = 0; kc < DIMD; kc += 64) {
    __syncthreads();
#pragma unroll
    for (int j = 0; j < 2; ++j) {            // stage capn[i] chunk
      int u = tid + 256 * j;
      int w = u >> 3, k8 = u & 7;
      int k8s = k8 ^ (w & 7);
      *(uint4*)&ca_s[w*64 + k8s*8] = *(const uint4*)(cb + (size_t)w*DIMD + kc + k8*8);
    }
#pragma unroll
    for (int j = 0; j < 2; ++j) {            // stage agn rows + cls + zero pad
      int u = tid + 256 * j;
      if (u < 384) {
        int rw = u >> 3, k8 = u & 7;
        int k8s = k8 ^ (rw & 7);
        uint4 v;
        if (rw < KEEPN)      v = *(const uint4*)(ab + (size_t)rw*DIMD + kc + k8*8);
        else if (rw == KEEPN) v = *(const uint4*)(clb + kc + k8*8);
        else                 v = make_uint4(0u, 0u, 0u, 0u);
        *(uint4*)&ag_s[rw*64 + k8s*8] = v;
      }
    }
    if (al < KEEPN) {                        // f32 att_y side-channel (score stability)
      const float* ar = agn + ((size_t)b*KEEPN + al)*DIMD + kc + ap*16;
      const float* gr = cglo + (size_t)i*DIMD + kc + ap*16;
#pragma unroll
      for (int j = 0; j < 16; j += 4) {
        f32x4 av = *(const f32x4*)(ar + j);
        f32x4 gv = *(const f32x4*)(gr + j);
        attv += av[0]*gv[0] + av[1]*gv[1] + av[2]*gv[2] + av[3]*gv[3];
      }
    }
    __syncthreads();
    int row = (wv << 4) + (lane & 15);
    int rb = lane & 15;
#pragma unroll
    for (int ks = 0; ks < 2; ++ks) {
      int kh = (lane >> 4) + ks * 4;
      bf16x8 a  = *(const bf16x8*)&ca_s[row*64 + (kh ^ (row & 7))*8];
      bf16x8 b0 = *(const bf16x8*)&ag_s[rb*64 + (kh ^ (rb & 7))*8];
      bf16x8 b1 = *(const bf16x8*)&ag_s[(16+rb)*64 + (kh ^ ((16+rb) & 7))*8];
      bf16x8 b2v = *(const bf16x8*)&ag_s[(32+rb)*64 + (kh ^ ((32+rb) & 7))*8];
      acc0  = __builtin_amdgcn_mfma_f32_16x16x32_bf16(a, b0, acc0, 0, 0, 0);
      acc1  = __builtin_amdgcn_mfma_f32_16x16x32_bf16(a, b1, acc1, 0, 0, 0);
      acc2v = __builtin_amdgcn_mfma_f32_16x16x32_bf16(a, b2v, acc2v, 0, 0, 0);
    }
  }
  {                                          // D2 -> LDS (C layout: col=lane&15, row=(lane>>4)*4+q)
    int cl = lane & 15, rr = lane >> 4;
#pragma unroll
    for (int q = 0; q < 4; ++q) {
      int w = (wv << 4) + rr*4 + q;
      d2_s[w*42 + cl] = acc0[q];
      d2_s[w*42 + 16 + cl] = acc1[q];
      if (cl < 8) d2_s[w*42 + 32 + cl] = acc2v[q];
    }
  }
  attv += __shfl_xor(attv, 1, 64);
  attv += __shfl_xor(attv, 2, 64);
  if (ap == 0 && al < KEEPN) atty_s[al] = attv;
  __syncthreads();
  if (wv == 0) {                             // E1: score, rank-select top-19, w_drop, ||extra||
    float sc = -FLT_MAX, nal = 0.f;
    if (lane < KEEPN) {
      sc = 0.8f * atty_s[lane] + 0.2f * attSelf[b*KEEPN + lane];
      nal = na_g[b*KEEPN + lane];
    }
    int rank = 0;
    for (int lp = 0; lp < KEEPN; ++lp) {
      float ov = __shfl(sc, lp, 64);
      if (ov > sc || (ov == sc && lp < lane)) rank++;
    }
    float selected = (lane < KEEPN && rank < 19) ? 1.f : 0.f;
    float uv = (lane < KEEPN && selected == 0.f) ? sc : -FLT_MAX;
    float m2 = wmaxr(uv);
    float pp = (lane < KEEPN && selected == 0.f) ? expf(sc - m2) : 0.f;
    float S = wsum(pp);
    float wd = pp / S;
    float rowdot = 0.f;
    const float* gr = G + (size_t)b*(KEEPN*KEEPN) + lane*KEEPN;
    for (int lp = 0; lp < KEEPN; ++lp) {
      float wdlp = __shfl(wd, lp, 64);
      if (lane < KEEPN) rowdot += wdlp * gr[lp];
    }
    float nex2 = wsum((lane < KEEPN) ? wd * rowdot : 0.f);
    if (lane < KEEPN) { wdna_s[lane] = wd * nal; sel_s[lane] = selected; }
    if (lane == 0) nex_s = fmaxf(sqrtf(fmaxf(nex2, 0.f)), 1e-12f);
  }
  __syncthreads();
  {                                          // E2: sim_max per word, masked mean
    int wl = lane & 15, lp4 = lane >> 4;
    int w = wv*16 + wl;
    int lbase = lp4*10, lcnt = (lp4 == 3) ? 9 : 10;
    float ed = 0.f, msl = -FLT_MAX;
    for (int j = 0; j < lcnt; ++j) {
      int l = lbase + j;
      float dv = d2_s[w*42 + l];
      ed += wdna_s[l] * dv;
      if (sel_s[l] > 0.5f) msl = fmaxf(msl, dv);
    }
    ed += __shfl_xor(ed, 16, 64); msl = fmaxf(msl, __shfl_xor(msl, 16, 64));
    ed += __shfl_xor(ed, 32, 64); msl = fmaxf(msl, __shfl_xor(msl, 32, 64));
    float pv = 0.f;
    if (lp4 == 0) {
      float d1 = d2_s[w*42 + 39];
      float smax = fmaxf(fmaxf(d1, msl), ed / nex_s);
      pv = (w < len) ? smax : 0.f;
    }
    pv += __shfl_xor(pv, 1, 64); pv += __shfl_xor(pv, 2, 64);
    pv += __shfl_xor(pv, 4, 64); pv += __shfl_xor(pv, 8, 64);
    if (lane == 0) part_s[wv] = pv;
  }
  __syncthreads();
  if (tid == 0)
    out[(size_t)b * 256 + i] = (part_s[0] + part_s[1] + part_s[2] + part_s[3]) / (float)len;
}

extern "C" void kernel_launch(void* const* d_in, const int* in_sizes, int n_in,
                              void* d_out, int out_size, void* d_ws, size_t ws_size,
                              hipStream_t stream) {
  const float* img = (const float*)d_in[0];
  const float* cap = (const float*)d_in[1];
  const int* lens = (const int*)d_in[2];
  const float* lng = (const float*)d_in[3];
  const float* lnb = (const float*)d_in[4];
  const float* W1 = (const float*)d_in[5];
  const float* b1 = (const float*)d_in[6];
  const float* W2 = (const float*)d_in[7];
  const float* b2 = (const float*)d_in[8];
  const float* scale = (const float*)d_in[9];
  float* out = (float*)d_out;
  char* ws = (char*)d_ws;
  size_t off = 0;
  auto alloc = [&](size_t bytes) -> void* {
    void* p = ws + off;
    off += (bytes + 255) & ~(size_t)255;
    return p;
  };
  float* agn            = (float*)alloc((size_t)256*39*512*4);
  unsigned short* agn_bf = (unsigned short*)alloc((size_t)256*39*512*2);
  unsigned short* capn_bf = (unsigned short*)alloc((size_t)256*64*512*2);
  unsigned short* clsn_bf = (unsigned short*)alloc((size_t)256*512*2);
  float* cglo    = (float*)alloc((size_t)256*512*4);
  float* gloraw  = (float*)alloc((size_t)256*512*4);
  float* na_g    = (float*)alloc((size_t)256*39*4);
  float* attSelf = (float*)alloc((size_t)256*39*4);
  float* G       = (float*)alloc((size_t)256*39*39*4);
  float* w1gT    = (float*)alloc((size_t)102*512*4);
  float* b1eff   = (float*)alloc((size_t)104*4);
  float* w2T     = (float*)alloc((size_t)39*104*4);
  float* wmat    = (float*)alloc((size_t)256*39*196*4);
  (void)in_sizes; (void)n_in; (void)out_size; (void)ws_size;

  hipLaunchKernelGGL(k0_prep, dim3(64), dim3(256), 0, stream,
                     W1, b1, W2, lng, lnb, w1gT, b1eff, w2T);
  hipLaunchKernelGGL(k1a, dim3(256), dim3(256), 0, stream,
                     img, w1gT, b1eff, w2T, b2, scale, wmat);
  hipLaunchKernelGGL(k1agg, dim3(256), dim3(256), 0, stream,
                     img, wmat, agn, agn_bf, na_g, gloraw);
  hipLaunchKernelGGL(k1b, dim3(256), dim3(256), 0, stream,
                     img, gloraw, agn, na_g, clsn_bf, attSelf, G);
  hipLaunchKernelGGL(k2, dim3(256), dim3(256), 0, stream,
                     cap, lens, capn_bf, cglo);
  hipLaunchKernelGGL(k3, dim3(256, 256), dim3(256), 0, stream,
                     capn_bf, agn_bf, clsn_bf, agn, cglo, na_g, attSelf, G, lens, out);
}

// Round 4
// 1817.297 us; speedup vs baseline: 1.4517x; 1.4517x over previous
//
#include <hip/hip_runtime.h>
#include <hip/hip_bf16.h>
#include <cfloat>
#include <cmath>

typedef float f32x4 __attribute__((ext_vector_type(4)));
typedef float f32x2 __attribute__((ext_vector_type(2)));
typedef short bf16x8 __attribute__((ext_vector_type(8)));

#define HID 102
#define KEEPN 39
#define DIMD 512

static __device__ __forceinline__ unsigned int f2bf(float v) {
  unsigned int b = __float_as_uint(v);
  return (b + 0x7FFFu + ((b >> 16) & 1u)) >> 16;  // RNE bf16
}
static __device__ __forceinline__ float wsum(float v) {
#pragma unroll
  for (int m = 1; m < 64; m <<= 1) v += __shfl_xor(v, m, 64);
  return v;
}
static __device__ __forceinline__ float wmaxr(float v) {
#pragma unroll
  for (int m = 1; m < 64; m <<= 1) v = fmaxf(v, __shfl_xor(v, m, 64));
  return v;
}
static __device__ __forceinline__ float bsum(float v, float* red4, int lane, int wid) {
  v = wsum(v);
  if (lane == 0) red4[wid] = v;
  __syncthreads();
  float r = red4[0] + red4[1] + red4[2] + red4[3];
  __syncthreads();
  return r;
}

// ---------------- K0: fold ln_g/ln_b into W1, transpose weights ----------------
__global__ __launch_bounds__(256) void k0_prep(
    const float* __restrict__ W1, const float* __restrict__ b1,
    const float* __restrict__ W2, const float* __restrict__ lng,
    const float* __restrict__ lnb,
    float* __restrict__ w1gT, float* __restrict__ b1eff, float* __restrict__ w2T) {
  int tid = blockIdx.x * 256 + threadIdx.x;
  for (int idx = tid; idx < HID * DIMD; idx += (int)gridDim.x * 256) {
    int c = idx >> 9, k = idx & 511;
    w1gT[idx] = lng[k] * W1[k * HID + c];
  }
  for (int idx = tid; idx < KEEPN * 104; idx += (int)gridDim.x * 256) {
    int l = idx / 104, k = idx - l * 104;
    w2T[idx] = (k < HID) ? W2[k * KEEPN + l] : 0.0f;
  }
  if (blockIdx.x == 0 && threadIdx.x < 104) {
    int c = threadIdx.x;
    float s = 0.f;
    if (c < HID) {
      s = b1[c];
      for (int k = 0; k < DIMD; ++k) s += lnb[k] * W1[k * HID + c];
    }
    b1eff[c] = s;
  }
}

// ---------------- K1a: per image: LN -> H1(gelu) -> W2 -> wmat ----------------
__global__ __launch_bounds__(256) void k1a(
    const float* __restrict__ img, const float* __restrict__ w1gT,
    const float* __restrict__ b1eff, const float* __restrict__ w2T,
    const float* __restrict__ b2, const float* __restrict__ scale,
    float* __restrict__ wmat) {
  int b = blockIdx.x;
  int tid = threadIdx.x;
  int lane = tid & 63, wid = tid >> 6;
  __shared__ float mu_s[196], rs_s[196];
  __shared__ __attribute__((aligned(16))) float w2t_s[KEEPN * 104];
  __shared__ float b1e_s[104];
  __shared__ __attribute__((aligned(16))) float uni[6864];
  float* x_s = uni;
  float* w1g_s = uni + 2176;
  float* h1_s = uni;
  const float* xb = img + (size_t)b * 197 * DIMD + DIMD;
  float scv = scale[0];
  for (int u = tid; u < KEEPN * 104 / 4; u += 256)
    ((f32x4*)w2t_s)[u] = ((const f32x4*)w2T)[u];
  if (tid < 104) b1e_s[tid] = b1eff[tid];
  for (int it = 0; it < 49; ++it) {
    int t = it * 4 + wid;
    const float* xr = xb + (size_t)t * DIMD + lane * 8;
    f32x4 v0 = *(const f32x4*)xr;
    f32x4 v1 = *(const f32x4*)(xr + 4);
    float s = v0[0]+v0[1]+v0[2]+v0[3]+v1[0]+v1[1]+v1[2]+v1[3];
    float q = v0[0]*v0[0]+v0[1]*v0[1]+v0[2]*v0[2]+v0[3]*v0[3]
            + v1[0]*v1[0]+v1[1]*v1[1]+v1[2]*v1[2]+v1[3]*v1[3];
    s = wsum(s); q = wsum(q);
    if (lane == 0) {
      float mu = s * (1.f/512.f);
      float var = q * (1.f/512.f) - mu*mu;
      mu_s[t] = mu;
      rs_s[t] = 1.f / sqrtf(var + 1e-5f);
    }
  }
  __syncthreads();
  int kh = tid >> 7, r = tid & 127, tg = r & 15, cg = r >> 4;
  for (int t0 = 0; t0 < 196; t0 += 64) {
    float acc[4][13] = {};
    for (int kc = 0; kc < DIMD; kc += 32) {
      __syncthreads();
#pragma unroll
      for (int j = 0; j < 2; ++j) {
        int u = tid + 256 * j;
        int tt = u >> 3, f = u & 7;
        int t = t0 + tt;
        if (t < 196) {
          f32x4 v = *(const f32x4*)(xb + (size_t)t * DIMD + kc + 4*f);
          float mu = mu_s[t], rs = rs_s[t];
          x_s[(4*f+0)*68 + tt] = (v[0]-mu)*rs;
          x_s[(4*f+1)*68 + tt] = (v[1]-mu)*rs;
          x_s[(4*f+2)*68 + tt] = (v[2]-mu)*rs;
          x_s[(4*f+3)*68 + tt] = (v[3]-mu)*rs;
        }
      }
#pragma unroll
      for (int j = 0; j < 4; ++j) {
        int u = tid + 256 * j;
        if (u < 816) {
          int c = u >> 3, f = u & 7;
          *(f32x4*)&w1g_s[c*36 + 4*f] = *(const f32x4*)(w1gT + c*DIMD + kc + 4*f);
        }
      }
      __syncthreads();
#pragma unroll
      for (int k4 = 0; k4 < 4; ++k4) {
        int kk = kh*16 + k4*4;
        f32x4 a0 = *(const f32x4*)&x_s[(kk+0)*68 + 4*tg];
        f32x4 a1 = *(const f32x4*)&x_s[(kk+1)*68 + 4*tg];
        f32x4 a2 = *(const f32x4*)&x_s[(kk+2)*68 + 4*tg];
        f32x4 a3 = *(const f32x4*)&x_s[(kk+3)*68 + 4*tg];
#pragma unroll
        for (int ci = 0; ci < 13; ++ci) {
          f32x4 w = *(const f32x4*)&w1g_s[(cg*13+ci)*36 + kk];
#pragma unroll
          for (int t = 0; t < 4; ++t)
            acc[t][ci] += a0[t]*w[0] + a1[t]*w[1] + a2[t]*w[2] + a3[t]*w[3];
        }
      }
    }
    __syncthreads();
    if (kh == 1) {
#pragma unroll
      for (int ci = 0; ci < 13; ++ci) {
        int c = cg*13 + ci;
        if (c < HID)
#pragma unroll
          for (int t = 0; t < 4; ++t) h1_s[c*66 + 4*tg + t] = acc[t][ci];
      }
    }
    __syncthreads();
    if (kh == 0) {
#pragma unroll
      for (int ci = 0; ci < 13; ++ci) {
        int c = cg*13 + ci;
        if (c < HID)
#pragma unroll
          for (int t = 0; t < 4; ++t) {
            float v = h1_s[c*66 + 4*tg + t] + acc[t][ci] + b1e_s[c];
            v = 0.5f * v * (1.f + erff(v * 0.70710678118654752f));
            h1_s[c*66 + 4*tg + t] = v;
          }
      }
    }
    if (tid < 128) h1_s[(HID + (tid >> 6))*66 + (tid & 63)] = 0.f;
    __syncthreads();
    {
      int t4 = tid & 31, lg = tid >> 5;
      int nl = (lg == 7) ? 4 : 5;
      float a2c[2][5] = {};
      for (int k = 0; k < 104; k += 4) {
        f32x4 wvv[5];
#pragma unroll
        for (int li = 0; li < 5; ++li) {
          if (li < nl) wvv[li] = *(const f32x4*)&w2t_s[(lg*5+li)*104 + k];
          else wvv[li] = (f32x4){0.f,0.f,0.f,0.f};
        }
#pragma unroll
        for (int j = 0; j < 4; ++j) {
          f32x2 h = *(const f32x2*)&h1_s[(k+j)*66 + 2*t4];
#pragma unroll
          for (int li = 0; li < 5; ++li) {
            a2c[0][li] += h[0]*wvv[li][j];
            a2c[1][li] += h[1]*wvv[li][j];
          }
        }
      }
#pragma unroll
      for (int li = 0; li < 5; ++li) {
        if (li < nl) {
          int l = lg*5 + li;
          float bb = b2[l];
#pragma unroll
          for (int tp = 0; tp < 2; ++tp) {
            int t = t0 + 2*t4 + tp;
            if (t < 196) wmat[((size_t)b*KEEPN + l)*196 + t] = (a2c[tp][li] + bb) * scv;
          }
        }
      }
    }
  }
}

// ---------------- K1agg: softmax over t + aggr + norms + mean; writes packed Bm ----------------
__global__ __launch_bounds__(256) void k1agg(
    const float* __restrict__ img, const float* __restrict__ wmat,
    float* __restrict__ agn, unsigned short* __restrict__ bm,
    float* __restrict__ na_g, float* __restrict__ gloraw) {
  int b = blockIdx.x, tid = threadIdx.x;
  int lane = tid & 63, wid = tid >> 6;
  __shared__ __attribute__((aligned(16))) float wm_s[KEEPN * 200];
  __shared__ float red_s[13 * 4];
  __shared__ float na_s[13];
  for (int u = tid; u < KEEPN * 49; u += 256) {
    int l = u / 49, t4 = u - l * 49;
    *(f32x4*)&wm_s[l*200 + 4*t4] = *(const f32x4*)(wmat + ((size_t)b*KEEPN + l)*196 + 4*t4);
  }
  __syncthreads();
  for (int l = wid; l < KEEPN; l += 4) {
    float v0 = wm_s[l*200 + lane];
    float v1 = wm_s[l*200 + 64 + lane];
    float v2 = wm_s[l*200 + 128 + lane];
    float v3 = (lane < 4) ? wm_s[l*200 + 192 + lane] : -FLT_MAX;
    float mx = wmaxr(fmaxf(fmaxf(v0, v1), fmaxf(v2, v3)));
    float e0 = expf(v0 - mx), e1 = expf(v1 - mx), e2 = expf(v2 - mx);
    float e3 = (lane < 4) ? expf(v3 - mx) : 0.f;
    float s = wsum(e0 + e1 + e2 + e3);
    float inv = 1.f / s;
    wm_s[l*200 + lane] = e0 * inv;
    wm_s[l*200 + 64 + lane] = e1 * inv;
    wm_s[l*200 + 128 + lane] = e2 * inv;
    if (lane < 4) wm_s[l*200 + 192 + lane] = e3 * inv;
  }
  __syncthreads();
  const float* xb = img + (size_t)b * 197 * DIMD + DIMD;
  int c0 = tid, c1 = tid + 256;
  float ms0 = 0.f, ms1 = 0.f;
  for (int lp = 0; lp < 3; ++lp) {
    int l0 = lp * 13;
    float a0[13] = {}, a1[13] = {};
    for (int t4 = 0; t4 < 49; ++t4) {
      float xx0[4], xx1[4];
#pragma unroll
      for (int j = 0; j < 4; ++j) {
        int t = 4*t4 + j;
        xx0[j] = xb[(size_t)t*DIMD + c0];
        xx1[j] = xb[(size_t)t*DIMD + c1];
      }
#pragma unroll
      for (int li = 0; li < 13; ++li) {
        f32x4 w = *(const f32x4*)&wm_s[(l0+li)*200 + 4*t4];
#pragma unroll
        for (int j = 0; j < 4; ++j) {
          a0[li] += w[j]*xx0[j];
          a1[li] += w[j]*xx1[j];
        }
      }
    }
#pragma unroll
    for (int li = 0; li < 13; ++li) {
      float p = wsum(a0[li]*a0[li] + a1[li]*a1[li]);
      if (lane == 0) red_s[li*4 + wid] = p;
    }
    __syncthreads();
    if (tid < 13) {
      float s = red_s[tid*4] + red_s[tid*4+1] + red_s[tid*4+2] + red_s[tid*4+3];
      float n = sqrtf(s);
      na_s[tid] = n;
      na_g[b*KEEPN + l0 + tid] = n;
    }
    __syncthreads();
#pragma unroll
    for (int li = 0; li < 13; ++li) {
      int l = l0 + li;
      float inv = 1.f / fmaxf(na_s[li], 1e-12f);
      size_t abase = ((size_t)b*KEEPN + l) * DIMD;
      size_t bbase = ((size_t)b*48 + l) * DIMD;
      float v0 = a0[li]*inv, v1 = a1[li]*inv;
      agn[abase + c0] = v0; agn[abase + c1] = v1;
      bm[bbase + c0] = (unsigned short)f2bf(v0);
      bm[bbase + c1] = (unsigned short)f2bf(v1);
      ms0 += a0[li]; ms1 += a1[li];
    }
    __syncthreads();
  }
  gloraw[(size_t)b*DIMD + c0] = ms0;
  gloraw[(size_t)b*DIMD + c1] = ms1;
}

// ---------------- K1b: glo, cls row of Bm + pad, att_self, Gram ----------------
__global__ __launch_bounds__(256) void k1b(
    const float* __restrict__ img, const float* __restrict__ gloraw,
    const float* __restrict__ agn, const float* __restrict__ na_g,
    unsigned short* __restrict__ bm, float* __restrict__ attSelf,
    float* __restrict__ G) {
  int b = blockIdx.x, tid = threadIdx.x;
  int lane = tid & 63, wid = tid >> 6;
  __shared__ float glo_s[DIMD];
  __shared__ float red4[4];
  int c0 = tid, c1 = tid + 256;
  float m0 = gloraw[(size_t)b*DIMD + c0] * (1.f/39.f);
  float m1 = gloraw[(size_t)b*DIMD + c1] * (1.f/39.f);
  float nt = bsum(m0*m0 + m1*m1, red4, lane, wid);
  float inv = 1.f / fmaxf(sqrtf(nt), 1e-12f);
  glo_s[c0] = m0*inv; glo_s[c1] = m1*inv;
  const float* cls = img + (size_t)b * 197 * DIMD;
  float x0 = cls[c0], x1 = cls[c1];
  float n2 = bsum(x0*x0 + x1*x1, red4, lane, wid);
  float inv2 = 1.f / fmaxf(sqrtf(n2), 1e-12f);
  bm[((size_t)b*48 + 39)*DIMD + c0] = (unsigned short)f2bf(x0*inv2);
  bm[((size_t)b*48 + 39)*DIMD + c1] = (unsigned short)f2bf(x1*inv2);
  // zero pad rows 40..47
  for (int u = tid; u < 8*DIMD; u += 256) {
    int rr = u >> 9, c = u & 511;
    bm[((size_t)b*48 + 40 + rr)*DIMD + c] = 0;
  }
  __syncthreads();
  for (int l = 0; l < KEEPN; ++l) {
    const float* ar = agn + ((size_t)b*KEEPN + l)*DIMD;
    float p = glo_s[c0]*ar[c0] + glo_s[c1]*ar[c1];
    float s = bsum(p, red4, lane, wid);
    if (tid == 0) attSelf[b*KEEPN + l] = s;
  }
  for (int p = tid; p < KEEPN*KEEPN; p += 256) {
    int l = p / KEEPN, lq = p - l*KEEPN;
    const float* A = agn + ((size_t)b*KEEPN + l)*DIMD;
    const float* B = agn + ((size_t)b*KEEPN + lq)*DIMD;
    float d = 0.f;
    for (int c = 0; c < DIMD; c += 4) {
      f32x4 va = *(const f32x4*)(A + c);
      f32x4 vb = *(const f32x4*)(B + c);
      d += va[0]*vb[0] + va[1]*vb[1] + va[2]*vb[2] + va[3]*vb[3];
    }
    G[(size_t)b*(KEEPN*KEEPN) + p] = d * na_g[b*KEEPN + l] * na_g[b*KEEPN + lq];
  }
}

// ---------------- K2: per caption: word norms (bf16) + cap_glo ----------------
__global__ __launch_bounds__(256) void k2(
    const float* __restrict__ cap, const int* __restrict__ lens,
    unsigned short* __restrict__ capn_bf, float* __restrict__ cglo) {
  int i = blockIdx.x, tid = threadIdx.x;
  int lane = tid & 63, wid = tid >> 6;
  __shared__ float red4[4];
  int len = lens[i];
  float nwf = (float)len;
  const float* cb = cap + (size_t)i * 64 * DIMD;
  for (int w = wid; w < 64; w += 4) {
    const float* xr = cb + (size_t)w*DIMD + lane*8;
    f32x4 v0 = *(const f32x4*)xr;
    f32x4 v1 = *(const f32x4*)(xr + 4);
    float q = v0[0]*v0[0]+v0[1]*v0[1]+v0[2]*v0[2]+v0[3]*v0[3]
            + v1[0]*v1[0]+v1[1]*v1[1]+v1[2]*v1[2]+v1[3]*v1[3];
    q = wsum(q);
    float inv = 1.f / fmaxf(sqrtf(q), 1e-12f);
    uint4 o;
    o.x = f2bf(v0[0]*inv) | (f2bf(v0[1]*inv) << 16);
    o.y = f2bf(v0[2]*inv) | (f2bf(v0[3]*inv) << 16);
    o.z = f2bf(v1[0]*inv) | (f2bf(v1[1]*inv) << 16);
    o.w = f2bf(v1[2]*inv) | (f2bf(v1[3]*inv) << 16);
    *(uint4*)(capn_bf + ((size_t)i*64 + w)*DIMD + lane*8) = o;
  }
  int c0 = tid, c1 = tid + 256;
  float s0 = 0.f, s1 = 0.f;
  for (int w = 0; w < len; ++w) {
    s0 += cb[(size_t)w*DIMD + c0];
    s1 += cb[(size_t)w*DIMD + c1];
  }
  s0 /= nwf; s1 /= nwf;
  float nt = bsum(s0*s0 + s1*s1, red4, lane, wid);
  float inv = 1.f / fmaxf(sqrtf(nt), 1e-12f);
  cglo[(size_t)i*DIMD + c0] = s0*inv;
  cglo[(size_t)i*DIMD + c1] = s1*inv;
}

// ---------------- K3p: per (image b, 64 captions): f32 attY + pair prep ----------------
__global__ __launch_bounds__(256) void k3p(
    const float* __restrict__ agn, const float* __restrict__ cglo,
    const float* __restrict__ attSelf, const float* __restrict__ na_g,
    const float* __restrict__ G,
    float* __restrict__ wdna_g, unsigned long long* __restrict__ selmask_g,
    float* __restrict__ nexinv_g) {
  int b = blockIdx.x, igrp = blockIdx.y;
  int tid = threadIdx.x, lane = tid & 63, wv = tid >> 6;
  __shared__ __attribute__((aligned(16))) float cg_s[64*36];
  __shared__ __attribute__((aligned(16))) float ag_s[40*36];
  __shared__ float sc_s[64*40];
  __shared__ float G_s[39*33];
  __shared__ float as_s[40];
  __shared__ float na_s[40];
  int ic0 = igrp * 64;
  for (int u = tid; u < KEEPN*KEEPN; u += 256) {
    int l = u / 39, q = u - l*39;
    G_s[l*33 + q] = G[(size_t)b*(KEEPN*KEEPN) + u];
  }
  if (tid < 39) { as_s[tid] = attSelf[b*KEEPN + tid]; na_s[tid] = na_g[b*KEEPN + tid]; }
  int i2 = tid & 31, l5 = tid >> 5;     // captions (i2, i2+32), l = 5*l5+li
  float acc0[5] = {}, acc1[5] = {};
  for (int kc = 0; kc < DIMD; kc += 32) {
    __syncthreads();
#pragma unroll
    for (int j = 0; j < 2; ++j) {
      int idx = tid + 256*j;
      int r = idx >> 3, cq = idx & 7;
      *(f32x4*)&cg_s[r*36 + 4*cq] = *(const f32x4*)&cglo[(size_t)(ic0 + r)*DIMD + kc + 4*cq];
    }
    if (tid < 320) {
      int r = tid >> 3, cq = tid & 7;
      f32x4 v = {0.f,0.f,0.f,0.f};
      if (r < 39) v = *(const f32x4*)&agn[((size_t)b*KEEPN + r)*DIMD + kc + 4*cq];
      *(f32x4*)&ag_s[r*36 + 4*cq] = v;
    }
    __syncthreads();
#pragma unroll
    for (int c4 = 0; c4 < 8; ++c4) {
      f32x4 a0 = *(const f32x4*)&cg_s[i2*36 + 4*c4];
      f32x4 a1 = *(const f32x4*)&cg_s[(i2+32)*36 + 4*c4];
#pragma unroll
      for (int li = 0; li < 5; ++li) {
        f32x4 bv = *(const f32x4*)&ag_s[(l5*5+li)*36 + 4*c4];
        acc0[li] += a0[0]*bv[0]+a0[1]*bv[1]+a0[2]*bv[2]+a0[3]*bv[3];
        acc1[li] += a1[0]*bv[0]+a1[1]*bv[1]+a1[2]*bv[2]+a1[3]*bv[3];
      }
    }
  }
  __syncthreads();
#pragma unroll
  for (int li = 0; li < 5; ++li) {
    int l = l5*5 + li;
    if (l < KEEPN) {
      sc_s[i2*40 + l]      = 0.8f*acc0[li] + 0.2f*as_s[l];
      sc_s[(i2+32)*40 + l] = 0.8f*acc1[li] + 0.2f*as_s[l];
    }
  }
  __syncthreads();
  for (int it = 0; it < 16; ++it) {
    int ic = it*4 + wv;
    size_t pair = (size_t)b*256 + ic0 + ic;
    float sc = (lane < KEEPN) ? sc_s[ic*40 + lane] : -FLT_MAX;
    int rank = 0;
    for (int lp = 0; lp < KEEPN; ++lp) {
      float ov = __shfl(sc, lp, 64);
      if (ov > sc || (ov == sc && lp < lane)) rank++;
    }
    bool selected = (lane < KEEPN && rank < 19);
    float uv = (lane < KEEPN && !selected) ? sc : -FLT_MAX;
    float m2 = wmaxr(uv);
    float pp = (lane < KEEPN && !selected) ? expf(sc - m2) : 0.f;
    float S = wsum(pp);
    float wd = pp / S;
    float rowdot = 0.f;
    for (int lp = 0; lp < KEEPN; ++lp) {
      float wdlp = __shfl(wd, lp, 64);
      if (lane < KEEPN) rowdot += wdlp * G_s[lane*33 + lp];
    }
    float nex2 = wsum((lane < KEEPN) ? wd*rowdot : 0.f);
    unsigned long long msk = __ballot(selected) | (1ull << 39);
    if (lane < 40) wdna_g[pair*40 + lane] = (lane < KEEPN) ? wd * na_s[lane] : 0.f;
    if (lane == 0) {
      selmask_g[pair] = msk;
      nexinv_g[pair] = 1.f / fmaxf(sqrtf(fmaxf(nex2, 0.f)), 1e-12f);
    }
  }
}

// ---------------- K3g: GEMM 64(words) x 384(8 images x 48) x 512 + fused epilogue ----------------
__global__ __launch_bounds__(256, 2) void k3g(
    const unsigned short* __restrict__ capn_bf, const unsigned short* __restrict__ bm,
    const float* __restrict__ wdna_g, const unsigned long long* __restrict__ selmask_g,
    const float* __restrict__ nexinv_g, const int* __restrict__ lens,
    float* __restrict__ out) {
  int bid = blockIdx.x;
  int btile = bid >> 8;        // 0..31 (8 images each)
  int i = bid & 255;           // caption
  int tid = threadIdx.x, lane = tid & 63, wv = tid >> 6;
  __shared__ __attribute__((aligned(16))) unsigned short A_s[64*64];   // 8 KB
  __shared__ __attribute__((aligned(16))) unsigned short B_s[384*64];  // 48 KB
  __shared__ float wd_s[8*48];
  __shared__ float sf_s[8*48];
  __shared__ float nx_s[8];
  int len = lens[i];
  const unsigned short* cb = capn_bf + (size_t)i * 64 * DIMD;
  const unsigned short* bb = bm + (size_t)btile * 384 * DIMD;
  // FIX (r3): stride the 384-entry prologue over 256 threads (was `if (tid<384)`
  // with only 256 threads -> wd_s/sf_s[256..383] and nx_s[6..7] uninitialized).
  for (int u = tid; u < 384; u += 256) {
    int g = u / 48, l = u - g*48;
    size_t pair = (size_t)(btile*8 + g)*256 + i;
    float wdv = 0.f, sfv = 0.f;
    if (l < 40) {
      wdv = wdna_g[pair*40 + l];
      sfv = ((selmask_g[pair] >> l) & 1ull) ? 1.f : 0.f;
    }
    wd_s[u] = wdv; sf_s[u] = sfv;
    if (l == 0) nx_s[g] = nexinv_g[pair];
  }
  f32x4 acc[4][6];
#pragma unroll
  for (int m = 0; m < 4; ++m)
#pragma unroll
    for (int n = 0; n < 6; ++n) acc[m][n] = (f32x4){0.f,0.f,0.f,0.f};
  for (int kc = 0; kc < 8; ++kc) {
    __syncthreads();
#pragma unroll
    for (int half = 0; half < 2; ++half) {
      uint4 vals[7];
#pragma unroll
      for (int j = 0; j < 7; ++j) {
        int u = (half*7 + j)*256 + tid;       // 0..3583
        const unsigned short* src;
        if (u < 512) { int row = u >> 3, k8 = u & 7; src = cb + (size_t)row*DIMD + kc*64 + k8*8; }
        else { int ub = u - 512; int row = ub >> 3, k8 = ub & 7; src = bb + (size_t)row*DIMD + kc*64 + k8*8; }
        vals[j] = *(const uint4*)src;
      }
#pragma unroll
      for (int j = 0; j < 7; ++j) {
        int u = (half*7 + j)*256 + tid;
        if (u < 512) { int row = u >> 3, k8 = u & 7; *(uint4*)&A_s[row*64 + (k8 ^ (row&7))*8] = vals[j]; }
        else { int ub = u - 512; int row = ub >> 3, k8 = ub & 7; *(uint4*)&B_s[row*64 + (k8 ^ (row&7))*8] = vals[j]; }
      }
    }
    __syncthreads();
#pragma unroll
    for (int ks = 0; ks < 2; ++ks) {
      int kh = 4*ks + (lane >> 4);
      bf16x8 af[4], bfr[6];
#pragma unroll
      for (int m = 0; m < 4; ++m) {
        int row = 16*m + (lane & 15);
        af[m] = *(const bf16x8*)&A_s[row*64 + (kh ^ (row&7))*8];
      }
#pragma unroll
      for (int n = 0; n < 6; ++n) {
        int row = 16*(6*wv + n) + (lane & 15);
        bfr[n] = *(const bf16x8*)&B_s[row*64 + (kh ^ (row&7))*8];
      }
#pragma unroll
      for (int m = 0; m < 4; ++m)
#pragma unroll
        for (int n = 0; n < 6; ++n)
          acc[m][n] = __builtin_amdgcn_mfma_f32_16x16x32_bf16(af[m], bfr[n], acc[m][n], 0, 0, 0);
    }
  }
  // fused epilogue: per wave, images g = 2*wv, 2*wv+1
  float pv[2] = {0.f, 0.f};
#pragma unroll
  for (int jj = 0; jj < 2; ++jj) {
    int g = 2*wv + jj;
    float nxi = nx_s[g];
#pragma unroll
    for (int m = 0; m < 4; ++m) {
      f32x4 ed = {0.f,0.f,0.f,0.f};
      f32x4 ms = {-FLT_MAX,-FLT_MAX,-FLT_MAX,-FLT_MAX};
#pragma unroll
      for (int j = 0; j < 3; ++j) {
        int l = 16*j + (lane & 15);
        float wdv = wd_s[g*48 + l];
        float sfv = sf_s[g*48 + l];
        f32x4 v = acc[m][3*jj + j];
#pragma unroll
        for (int q = 0; q < 4; ++q) {
          ed[q] += wdv * v[q];
          ms[q] = fmaxf(ms[q], (sfv > 0.5f) ? v[q] : -FLT_MAX);
        }
      }
#pragma unroll
      for (int sh = 1; sh < 16; sh <<= 1) {
#pragma unroll
        for (int q = 0; q < 4; ++q) {
          ed[q] += __shfl_xor(ed[q], sh, 64);
          ms[q] = fmaxf(ms[q], __shfl_xor(ms[q], sh, 64));
        }
      }
      // Only one lane per 16-lane group contributes (values are identical
      // across the group after the butterfly reduce).
      if ((lane & 15) == 0) {
#pragma unroll
        for (int q = 0; q < 4; ++q) {
          int r2 = 16*m + (lane >> 4)*4 + q;
          float smax = fmaxf(ms[q], ed[q]*nxi);
          pv[jj] += (r2 < len) ? smax : 0.f;
        }
      }
    }
    pv[jj] += __shfl_xor(pv[jj], 16, 64);
    pv[jj] += __shfl_xor(pv[jj], 32, 64);
  }
  if (lane == 0) {
#pragma unroll
    for (int jj = 0; jj < 2; ++jj) {
      int g = 2*wv + jj;
      out[(size_t)(btile*8 + g)*256 + i] = pv[jj] / (float)len;
    }
  }
}

extern "C" void kernel_launch(void* const* d_in, const int* in_sizes, int n_in,
                              void* d_out, int out_size, void* d_ws, size_t ws_size,
                              hipStream_t stream) {
  const float* img = (const float*)d_in[0];
  const float* cap = (const float*)d_in[1];
  const int* lens = (const int*)d_in[2];
  const float* lng = (const float*)d_in[3];
  const float* lnb = (const float*)d_in[4];
  const float* W1 = (const float*)d_in[5];
  const float* b1 = (const float*)d_in[6];
  const float* W2 = (const float*)d_in[7];
  const float* b2 = (const float*)d_in[8];
  const float* scale = (const float*)d_in[9];
  float* out = (float*)d_out;
  char* ws = (char*)d_ws;
  size_t off = 0;
  auto alloc = [&](size_t bytes) -> void* {
    void* p = ws + off;
    off += (bytes + 255) & ~(size_t)255;
    return p;
  };
  float* agn             = (float*)alloc((size_t)256*39*512*4);
  unsigned short* bm     = (unsigned short*)alloc((size_t)256*48*512*2);
  unsigned short* capn_bf = (unsigned short*)alloc((size_t)256*64*512*2);
  float* cglo    = (float*)alloc((size_t)256*512*4);
  float* gloraw  = (float*)alloc((size_t)256*512*4);
  float* na_g    = (float*)alloc((size_t)256*39*4);
  float* attSelf = (float*)alloc((size_t)256*39*4);
  float* G       = (float*)alloc((size_t)256*39*39*4);
  float* w1gT    = (float*)alloc((size_t)102*512*4);
  float* b1eff   = (float*)alloc((size_t)104*4);
  float* w2T     = (float*)alloc((size_t)39*104*4);
  float* wmat    = (float*)alloc((size_t)256*39*196*4);
  float* wdna_g  = (float*)alloc((size_t)65536*40*4);
  unsigned long long* selmask_g = (unsigned long long*)alloc((size_t)65536*8);
  float* nexinv_g = (float*)alloc((size_t)65536*4);
  (void)in_sizes; (void)n_in; (void)out_size; (void)ws_size;

  hipLaunchKernelGGL(k0_prep, dim3(64), dim3(256), 0, stream,
                     W1, b1, W2, lng, lnb, w1gT, b1eff, w2T);
  hipLaunchKernelGGL(k1a, dim3(256), dim3(256), 0, stream,
                     img, w1gT, b1eff, w2T, b2, scale, wmat);
  hipLaunchKernelGGL(k1agg, dim3(256), dim3(256), 0, stream,
                     img, wmat, agn, bm, na_g, gloraw);
  hipLaunchKernelGGL(k1b, dim3(256), dim3(256), 0, stream,
                     img, gloraw, agn, na_g, bm, attSelf, G);
  hipLaunchKernelGGL(k2, dim3(256), dim3(256), 0, stream,
                     cap, lens, capn_bf, cglo);
  hipLaunchKernelGGL(k3p, dim3(256, 4), dim3(256), 0, stream,
                     agn, cglo, attSelf, na_g, G, wdna_g, selmask_g, nexinv_g);
  hipLaunchKernelGGL(k3g, dim3(8192), dim3(256), 0, stream,
                     capn_bf, bm, wdna_g, selmask_g, nexinv_g, lens, out);
}

// Round 5
// 1285.103 us; speedup vs baseline: 2.0528x; 1.4141x over previous
//
#include <hip/hip_runtime.h>
#include <hip/hip_bf16.h>
#include <cfloat>
#include <cmath>

typedef float f32x4 __attribute__((ext_vector_type(4)));
typedef float f32x2 __attribute__((ext_vector_type(2)));
typedef short bf16x8 __attribute__((ext_vector_type(8)));

#define HID 102
#define KEEPN 39
#define DIMD 512

static __device__ __forceinline__ unsigned int f2bf(float v) {
  unsigned int b = __float_as_uint(v);
  return (b + 0x7FFFu + ((b >> 16) & 1u)) >> 16;  // RNE bf16
}
static __device__ __forceinline__ float wsum(float v) {
#pragma unroll
  for (int m = 1; m < 64; m <<= 1) v += __shfl_xor(v, m, 64);
  return v;
}
static __device__ __forceinline__ float wmaxr(float v) {
#pragma unroll
  for (int m = 1; m < 64; m <<= 1) v = fmaxf(v, __shfl_xor(v, m, 64));
  return v;
}
static __device__ __forceinline__ float bsum(float v, float* red4, int lane, int wid) {
  v = wsum(v);
  if (lane == 0) red4[wid] = v;
  __syncthreads();
  float r = red4[0] + red4[1] + red4[2] + red4[3];
  __syncthreads();
  return r;
}

// ---------------- K0: fold ln_g/ln_b into W1, transpose weights ----------------
__global__ __launch_bounds__(256) void k0_prep(
    const float* __restrict__ W1, const float* __restrict__ b1,
    const float* __restrict__ W2, const float* __restrict__ lng,
    const float* __restrict__ lnb,
    float* __restrict__ w1gT, float* __restrict__ b1eff, float* __restrict__ w2T) {
  int tid = blockIdx.x * 256 + threadIdx.x;
  for (int idx = tid; idx < HID * DIMD; idx += (int)gridDim.x * 256) {
    int c = idx >> 9, k = idx & 511;
    w1gT[idx] = lng[k] * W1[k * HID + c];
  }
  for (int idx = tid; idx < KEEPN * 104; idx += (int)gridDim.x * 256) {
    int l = idx / 104, k = idx - l * 104;
    w2T[idx] = (k < HID) ? W2[k * KEEPN + l] : 0.0f;
  }
  if (blockIdx.x == 0 && threadIdx.x < 104) {
    int c = threadIdx.x;
    float s = 0.f;
    if (c < HID) {
      s = b1[c];
      for (int k = 0; k < DIMD; ++k) s += lnb[k] * W1[k * HID + c];
    }
    b1eff[c] = s;
  }
}

// ---------------- K1a: per image: LN -> H1(gelu) -> W2 -> wmat ----------------
// r4: anti-spill pass. WRITE_SIZE showed 555 MB/dispatch of scratch traffic at
// VGPR=256 / occupancy 12% -> compiler over-unrolled the barrier'd loops.
// Pin unrolls + cap regs at 128 (2 blocks/CU).
__global__ __launch_bounds__(256, 2) void k1a(
    const float* __restrict__ img, const float* __restrict__ w1gT,
    const float* __restrict__ b1eff, const float* __restrict__ w2T,
    const float* __restrict__ b2, const float* __restrict__ scale,
    float* __restrict__ wmat) {
  int b = blockIdx.x;
  int tid = threadIdx.x;
  int lane = tid & 63, wid = tid >> 6;
  __shared__ float mu_s[196], rs_s[196];
  __shared__ __attribute__((aligned(16))) float w2t_s[KEEPN * 104];
  __shared__ float b1e_s[104];
  __shared__ __attribute__((aligned(16))) float uni[6864];
  float* x_s = uni;
  float* w1g_s = uni + 2176;
  float* h1_s = uni;
  const float* xb = img + (size_t)b * 197 * DIMD + DIMD;
  float scv = scale[0];
  for (int u = tid; u < KEEPN * 104 / 4; u += 256)
    ((f32x4*)w2t_s)[u] = ((const f32x4*)w2T)[u];
  if (tid < 104) b1e_s[tid] = b1eff[tid];
#pragma unroll 1
  for (int it = 0; it < 49; ++it) {
    int t = it * 4 + wid;
    const float* xr = xb + (size_t)t * DIMD + lane * 8;
    f32x4 v0 = *(const f32x4*)xr;
    f32x4 v1 = *(const f32x4*)(xr + 4);
    float s = v0[0]+v0[1]+v0[2]+v0[3]+v1[0]+v1[1]+v1[2]+v1[3];
    float q = v0[0]*v0[0]+v0[1]*v0[1]+v0[2]*v0[2]+v0[3]*v0[3]
            + v1[0]*v1[0]+v1[1]*v1[1]+v1[2]*v1[2]+v1[3]*v1[3];
    s = wsum(s); q = wsum(q);
    if (lane == 0) {
      float mu = s * (1.f/512.f);
      float var = q * (1.f/512.f) - mu*mu;
      mu_s[t] = mu;
      rs_s[t] = 1.f / sqrtf(var + 1e-5f);
    }
  }
  __syncthreads();
  int kh = tid >> 7, r = tid & 127, tg = r & 15, cg = r >> 4;
#pragma unroll 1
  for (int t0 = 0; t0 < 196; t0 += 64) {
    float acc[4][13] = {};
#pragma unroll 1
    for (int kc = 0; kc < DIMD; kc += 32) {
      __syncthreads();
#pragma unroll
      for (int j = 0; j < 2; ++j) {
        int u = tid + 256 * j;
        int tt = u >> 3, f = u & 7;
        int t = t0 + tt;
        if (t < 196) {
          f32x4 v = *(const f32x4*)(xb + (size_t)t * DIMD + kc + 4*f);
          float mu = mu_s[t], rs = rs_s[t];
          x_s[(4*f+0)*68 + tt] = (v[0]-mu)*rs;
          x_s[(4*f+1)*68 + tt] = (v[1]-mu)*rs;
          x_s[(4*f+2)*68 + tt] = (v[2]-mu)*rs;
          x_s[(4*f+3)*68 + tt] = (v[3]-mu)*rs;
        }
      }
#pragma unroll
      for (int j = 0; j < 4; ++j) {
        int u = tid + 256 * j;
        if (u < 816) {
          int c = u >> 3, f = u & 7;
          *(f32x4*)&w1g_s[c*36 + 4*f] = *(const f32x4*)(w1gT + c*DIMD + kc + 4*f);
        }
      }
      __syncthreads();
#pragma unroll
      for (int k4 = 0; k4 < 4; ++k4) {
        int kk = kh*16 + k4*4;
        f32x4 a0 = *(const f32x4*)&x_s[(kk+0)*68 + 4*tg];
        f32x4 a1 = *(const f32x4*)&x_s[(kk+1)*68 + 4*tg];
        f32x4 a2 = *(const f32x4*)&x_s[(kk+2)*68 + 4*tg];
        f32x4 a3 = *(const f32x4*)&x_s[(kk+3)*68 + 4*tg];
#pragma unroll
        for (int ci = 0; ci < 13; ++ci) {
          f32x4 w = *(const f32x4*)&w1g_s[(cg*13+ci)*36 + kk];
#pragma unroll
          for (int t = 0; t < 4; ++t)
            acc[t][ci] += a0[t]*w[0] + a1[t]*w[1] + a2[t]*w[2] + a3[t]*w[3];
        }
      }
    }
    __syncthreads();
    if (kh == 1) {
#pragma unroll
      for (int ci = 0; ci < 13; ++ci) {
        int c = cg*13 + ci;
        if (c < HID)
#pragma unroll
          for (int t = 0; t < 4; ++t) h1_s[c*66 + 4*tg + t] = acc[t][ci];
      }
    }
    __syncthreads();
    if (kh == 0) {
#pragma unroll
      for (int ci = 0; ci < 13; ++ci) {
        int c = cg*13 + ci;
        if (c < HID)
#pragma unroll
          for (int t = 0; t < 4; ++t) {
            float v = h1_s[c*66 + 4*tg + t] + acc[t][ci] + b1e_s[c];
            v = 0.5f * v * (1.f + erff(v * 0.70710678118654752f));
            h1_s[c*66 + 4*tg + t] = v;
          }
      }
    }
    if (tid < 128) h1_s[(HID + (tid >> 6))*66 + (tid & 63)] = 0.f;
    __syncthreads();
    {
      int t4 = tid & 31, lg = tid >> 5;
      int nl = (lg == 7) ? 4 : 5;
      float a2c[2][5] = {};
#pragma unroll 2
      for (int k = 0; k < 104; k += 4) {
        f32x4 wvv[5];
#pragma unroll
        for (int li = 0; li < 5; ++li) {
          if (li < nl) wvv[li] = *(const f32x4*)&w2t_s[(lg*5+li)*104 + k];
          else wvv[li] = (f32x4){0.f,0.f,0.f,0.f};
        }
#pragma unroll
        for (int j = 0; j < 4; ++j) {
          f32x2 h = *(const f32x2*)&h1_s[(k+j)*66 + 2*t4];
#pragma unroll
          for (int li = 0; li < 5; ++li) {
            a2c[0][li] += h[0]*wvv[li][j];
            a2c[1][li] += h[1]*wvv[li][j];
          }
        }
      }
#pragma unroll
      for (int li = 0; li < 5; ++li) {
        if (li < nl) {
          int l = lg*5 + li;
          float bb = b2[l];
#pragma unroll
          for (int tp = 0; tp < 2; ++tp) {
            int t = t0 + 2*t4 + tp;
            if (t < 196) wmat[((size_t)b*KEEPN + l)*196 + t] = (a2c[tp][li] + bb) * scv;
          }
        }
      }
    }
  }
}

// ---------------- K1agg: softmax over t + aggr + norms + mean; writes packed Bm ----------------
// r4: thread owns columns {2*tid, 2*tid+1} -> f32x2 img loads (G13), paired stores.
__global__ __launch_bounds__(256) void k1agg(
    const float* __restrict__ img, const float* __restrict__ wmat,
    float* __restrict__ agn, unsigned short* __restrict__ bm,
    float* __restrict__ na_g, float* __restrict__ gloraw) {
  int b = blockIdx.x, tid = threadIdx.x;
  int lane = tid & 63, wid = tid >> 6;
  __shared__ __attribute__((aligned(16))) float wm_s[KEEPN * 200];
  __shared__ float red_s[13 * 4];
  __shared__ float na_s[13];
  for (int u = tid; u < KEEPN * 49; u += 256) {
    int l = u / 49, t4 = u - l * 49;
    *(f32x4*)&wm_s[l*200 + 4*t4] = *(const f32x4*)(wmat + ((size_t)b*KEEPN + l)*196 + 4*t4);
  }
  __syncthreads();
  for (int l = wid; l < KEEPN; l += 4) {
    float v0 = wm_s[l*200 + lane];
    float v1 = wm_s[l*200 + 64 + lane];
    float v2 = wm_s[l*200 + 128 + lane];
    float v3 = (lane < 4) ? wm_s[l*200 + 192 + lane] : -FLT_MAX;
    float mx = wmaxr(fmaxf(fmaxf(v0, v1), fmaxf(v2, v3)));
    float e0 = expf(v0 - mx), e1 = expf(v1 - mx), e2 = expf(v2 - mx);
    float e3 = (lane < 4) ? expf(v3 - mx) : 0.f;
    float s = wsum(e0 + e1 + e2 + e3);
    float inv = 1.f / s;
    wm_s[l*200 + lane] = e0 * inv;
    wm_s[l*200 + 64 + lane] = e1 * inv;
    wm_s[l*200 + 128 + lane] = e2 * inv;
    if (lane < 4) wm_s[l*200 + 192 + lane] = e3 * inv;
  }
  __syncthreads();
  const float* xb = img + (size_t)b * 197 * DIMD + DIMD;
  int cc = 2 * tid;
  float ms0 = 0.f, ms1 = 0.f;
#pragma unroll 1
  for (int lp = 0; lp < 3; ++lp) {
    int l0 = lp * 13;
    float a0[13] = {}, a1[13] = {};
#pragma unroll 1
    for (int t4 = 0; t4 < 49; ++t4) {
      f32x2 xx[4];
#pragma unroll
      for (int j = 0; j < 4; ++j) {
        int t = 4*t4 + j;
        xx[j] = *(const f32x2*)(xb + (size_t)t*DIMD + cc);
      }
#pragma unroll
      for (int li = 0; li < 13; ++li) {
        f32x4 w = *(const f32x4*)&wm_s[(l0+li)*200 + 4*t4];
#pragma unroll
        for (int j = 0; j < 4; ++j) {
          a0[li] += w[j]*xx[j][0];
          a1[li] += w[j]*xx[j][1];
        }
      }
    }
#pragma unroll
    for (int li = 0; li < 13; ++li) {
      float p = wsum(a0[li]*a0[li] + a1[li]*a1[li]);
      if (lane == 0) red_s[li*4 + wid] = p;
    }
    __syncthreads();
    if (tid < 13) {
      float s = red_s[tid*4] + red_s[tid*4+1] + red_s[tid*4+2] + red_s[tid*4+3];
      float n = sqrtf(s);
      na_s[tid] = n;
      na_g[b*KEEPN + l0 + tid] = n;
    }
    __syncthreads();
#pragma unroll
    for (int li = 0; li < 13; ++li) {
      int l = l0 + li;
      float inv = 1.f / fmaxf(na_s[li], 1e-12f);
      size_t abase = ((size_t)b*KEEPN + l) * DIMD;
      size_t bbase = ((size_t)b*48 + l) * DIMD;
      float v0 = a0[li]*inv, v1 = a1[li]*inv;
      *(f32x2*)&agn[abase + cc] = (f32x2){v0, v1};
      *(unsigned int*)&bm[bbase + cc] = f2bf(v0) | (f2bf(v1) << 16);
      ms0 += a0[li]; ms1 += a1[li];
    }
    __syncthreads();
  }
  *(f32x2*)&gloraw[(size_t)b*DIMD + cc] = (f32x2){ms0, ms1};
}

// ---------------- K1b: glo, cls row of Bm + pad, att_self, Gram ----------------
__global__ __launch_bounds__(256) void k1b(
    const float* __restrict__ img, const float* __restrict__ gloraw,
    const float* __restrict__ agn, const float* __restrict__ na_g,
    unsigned short* __restrict__ bm, float* __restrict__ attSelf,
    float* __restrict__ G) {
  int b = blockIdx.x, tid = threadIdx.x;
  int lane = tid & 63, wid = tid >> 6;
  __shared__ float glo_s[DIMD];
  __shared__ float red4[4];
  int c0 = tid, c1 = tid + 256;
  float m0 = gloraw[(size_t)b*DIMD + c0] * (1.f/39.f);
  float m1 = gloraw[(size_t)b*DIMD + c1] * (1.f/39.f);
  float nt = bsum(m0*m0 + m1*m1, red4, lane, wid);
  float inv = 1.f / fmaxf(sqrtf(nt), 1e-12f);
  glo_s[c0] = m0*inv; glo_s[c1] = m1*inv;
  const float* cls = img + (size_t)b * 197 * DIMD;
  float x0 = cls[c0], x1 = cls[c1];
  float n2 = bsum(x0*x0 + x1*x1, red4, lane, wid);
  float inv2 = 1.f / fmaxf(sqrtf(n2), 1e-12f);
  bm[((size_t)b*48 + 39)*DIMD + c0] = (unsigned short)f2bf(x0*inv2);
  bm[((size_t)b*48 + 39)*DIMD + c1] = (unsigned short)f2bf(x1*inv2);
  // zero pad rows 40..47
  for (int u = tid; u < 8*DIMD; u += 256) {
    int rr = u >> 9, c = u & 511;
    bm[((size_t)b*48 + 40 + rr)*DIMD + c] = 0;
  }
  __syncthreads();
#pragma unroll 1
  for (int l = 0; l < KEEPN; ++l) {
    const float* ar = agn + ((size_t)b*KEEPN + l)*DIMD;
    float p = glo_s[c0]*ar[c0] + glo_s[c1]*ar[c1];
    float s = bsum(p, red4, lane, wid);
    if (tid == 0) attSelf[b*KEEPN + l] = s;
  }
#pragma unroll 1
  for (int p = tid; p < KEEPN*KEEPN; p += 256) {
    int l = p / KEEPN, lq = p - l*KEEPN;
    const float* A = agn + ((size_t)b*KEEPN + l)*DIMD;
    const float* B = agn + ((size_t)b*KEEPN + lq)*DIMD;
    float d = 0.f;
#pragma unroll 4
    for (int c = 0; c < DIMD; c += 4) {
      f32x4 va = *(const f32x4*)(A + c);
      f32x4 vb = *(const f32x4*)(B + c);
      d += va[0]*vb[0] + va[1]*vb[1] + va[2]*vb[2] + va[3]*vb[3];
    }
    G[(size_t)b*(KEEPN*KEEPN) + p] = d * na_g[b*KEEPN + l] * na_g[b*KEEPN + lq];
  }
}

// ---------------- K2: per caption: word norms (bf16) + cap_glo ----------------
__global__ __launch_bounds__(256) void k2(
    const float* __restrict__ cap, const int* __restrict__ lens,
    unsigned short* __restrict__ capn_bf, float* __restrict__ cglo) {
  int i = blockIdx.x, tid = threadIdx.x;
  int lane = tid & 63, wid = tid >> 6;
  __shared__ float red4[4];
  int len = lens[i];
  float nwf = (float)len;
  const float* cb = cap + (size_t)i * 64 * DIMD;
  for (int w = wid; w < 64; w += 4) {
    const float* xr = cb + (size_t)w*DIMD + lane*8;
    f32x4 v0 = *(const f32x4*)xr;
    f32x4 v1 = *(const f32x4*)(xr + 4);
    float q = v0[0]*v0[0]+v0[1]*v0[1]+v0[2]*v0[2]+v0[3]*v0[3]
            + v1[0]*v1[0]+v1[1]*v1[1]+v1[2]*v1[2]+v1[3]*v1[3];
    q = wsum(q);
    float inv = 1.f / fmaxf(sqrtf(q), 1e-12f);
    uint4 o;
    o.x = f2bf(v0[0]*inv) | (f2bf(v0[1]*inv) << 16);
    o.y = f2bf(v0[2]*inv) | (f2bf(v0[3]*inv) << 16);
    o.z = f2bf(v1[0]*inv) | (f2bf(v1[1]*inv) << 16);
    o.w = f2bf(v1[2]*inv) | (f2bf(v1[3]*inv) << 16);
    *(uint4*)(capn_bf + ((size_t)i*64 + w)*DIMD + lane*8) = o;
  }
  int c0 = tid, c1 = tid + 256;
  float s0 = 0.f, s1 = 0.f;
#pragma unroll 1
  for (int w = 0; w < len; ++w) {
    s0 += cb[(size_t)w*DIMD + c0];
    s1 += cb[(size_t)w*DIMD + c1];
  }
  s0 /= nwf; s1 /= nwf;
  float nt = bsum(s0*s0 + s1*s1, red4, lane, wid);
  float inv = 1.f / fmaxf(sqrtf(nt), 1e-12f);
  cglo[(size_t)i*DIMD + c0] = s0*inv;
  cglo[(size_t)i*DIMD + c1] = s1*inv;
}

// ---------------- K3p: per (image b, 64 captions): f32 attY + pair prep ----------------
__global__ __launch_bounds__(256) void k3p(
    const float* __restrict__ agn, const float* __restrict__ cglo,
    const float* __restrict__ attSelf, const float* __restrict__ na_g,
    const float* __restrict__ G,
    float* __restrict__ wdna_g, unsigned long long* __restrict__ selmask_g,
    float* __restrict__ nexinv_g) {
  int b = blockIdx.x, igrp = blockIdx.y;
  int tid = threadIdx.x, lane = tid & 63, wv = tid >> 6;
  __shared__ __attribute__((aligned(16))) float cg_s[64*36];
  __shared__ __attribute__((aligned(16))) float ag_s[40*36];
  __shared__ float sc_s[64*40];
  __shared__ float G_s[39*33];
  __shared__ float as_s[40];
  __shared__ float na_s[40];
  int ic0 = igrp * 64;
  for (int u = tid; u < KEEPN*KEEPN; u += 256) {
    int l = u / 39, q = u - l*39;
    G_s[l*33 + q] = G[(size_t)b*(KEEPN*KEEPN) + u];
  }
  if (tid < 39) { as_s[tid] = attSelf[b*KEEPN + tid]; na_s[tid] = na_g[b*KEEPN + tid]; }
  int i2 = tid & 31, l5 = tid >> 5;     // captions (i2, i2+32), l = 5*l5+li
  float acc0[5] = {}, acc1[5] = {};
#pragma unroll 1
  for (int kc = 0; kc < DIMD; kc += 32) {
    __syncthreads();
#pragma unroll
    for (int j = 0; j < 2; ++j) {
      int idx = tid + 256*j;
      int r = idx >> 3, cq = idx & 7;
      *(f32x4*)&cg_s[r*36 + 4*cq] = *(const f32x4*)&cglo[(size_t)(ic0 + r)*DIMD + kc + 4*cq];
    }
    if (tid < 320) {
      int r = tid >> 3, cq = tid & 7;
      f32x4 v = {0.f,0.f,0.f,0.f};
      if (r < 39) v = *(const f32x4*)&agn[((size_t)b*KEEPN + r)*DIMD + kc + 4*cq];
      *(f32x4*)&ag_s[r*36 + 4*cq] = v;
    }
    __syncthreads();
#pragma unroll
    for (int c4 = 0; c4 < 8; ++c4) {
      f32x4 a0 = *(const f32x4*)&cg_s[i2*36 + 4*c4];
      f32x4 a1 = *(const f32x4*)&cg_s[(i2+32)*36 + 4*c4];
#pragma unroll
      for (int li = 0; li < 5; ++li) {
        f32x4 bv = *(const f32x4*)&ag_s[(l5*5+li)*36 + 4*c4];
        acc0[li] += a0[0]*bv[0]+a0[1]*bv[1]+a0[2]*bv[2]+a0[3]*bv[3];
        acc1[li] += a1[0]*bv[0]+a1[1]*bv[1]+a1[2]*bv[2]+a1[3]*bv[3];
      }
    }
  }
  __syncthreads();
#pragma unroll
  for (int li = 0; li < 5; ++li) {
    int l = l5*5 + li;
    if (l < KEEPN) {
      sc_s[i2*40 + l]      = 0.8f*acc0[li] + 0.2f*as_s[l];
      sc_s[(i2+32)*40 + l] = 0.8f*acc1[li] + 0.2f*as_s[l];
    }
  }
  __syncthreads();
#pragma unroll 1
  for (int it = 0; it < 16; ++it) {
    int ic = it*4 + wv;
    size_t pair = (size_t)b*256 + ic0 + ic;
    float sc = (lane < KEEPN) ? sc_s[ic*40 + lane] : -FLT_MAX;
    int rank = 0;
    for (int lp = 0; lp < KEEPN; ++lp) {
      float ov = __shfl(sc, lp, 64);
      if (ov > sc || (ov == sc && lp < lane)) rank++;
    }
    bool selected = (lane < KEEPN && rank < 19);
    float uv = (lane < KEEPN && !selected) ? sc : -FLT_MAX;
    float m2 = wmaxr(uv);
    float pp = (lane < KEEPN && !selected) ? expf(sc - m2) : 0.f;
    float S = wsum(pp);
    float wd = pp / S;
    float rowdot = 0.f;
    for (int lp = 0; lp < KEEPN; ++lp) {
      float wdlp = __shfl(wd, lp, 64);
      if (lane < KEEPN) rowdot += wdlp * G_s[lane*33 + lp];
    }
    float nex2 = wsum((lane < KEEPN) ? wd*rowdot : 0.f);
    unsigned long long msk = __ballot(selected) | (1ull << 39);
    if (lane < 40) wdna_g[pair*40 + lane] = (lane < KEEPN) ? wd * na_s[lane] : 0.f;
    if (lane == 0) {
      selmask_g[pair] = msk;
      nexinv_g[pair] = 1.f / fmaxf(sqrtf(fmaxf(nex2, 0.f)), 1e-12f);
    }
  }
}

// ---------------- K3g: GEMM 64(words) x 384(8 images x 48) x 512 + fused epilogue ----------------
__global__ __launch_bounds__(256, 2) void k3g(
    const unsigned short* __restrict__ capn_bf, const unsigned short* __restrict__ bm,
    const float* __restrict__ wdna_g, const unsigned long long* __restrict__ selmask_g,
    const float* __restrict__ nexinv_g, const int* __restrict__ lens,
    float* __restrict__ out) {
  int bid = blockIdx.x;
  int btile = bid >> 8;        // 0..31 (8 images each)
  int i = bid & 255;           // caption
  int tid = threadIdx.x, lane = tid & 63, wv = tid >> 6;
  __shared__ __attribute__((aligned(16))) unsigned short A_s[64*64];   // 8 KB
  __shared__ __attribute__((aligned(16))) unsigned short B_s[384*64];  // 48 KB
  __shared__ float wd_s[8*48];
  __shared__ float sf_s[8*48];
  __shared__ float nx_s[8];
  int len = lens[i];
  const unsigned short* cb = capn_bf + (size_t)i * 64 * DIMD;
  const unsigned short* bb = bm + (size_t)btile * 384 * DIMD;
  for (int u = tid; u < 384; u += 256) {
    int g = u / 48, l = u - g*48;
    size_t pair = (size_t)(btile*8 + g)*256 + i;
    float wdv = 0.f, sfv = 0.f;
    if (l < 40) {
      wdv = wdna_g[pair*40 + l];
      sfv = ((selmask_g[pair] >> l) & 1ull) ? 1.f : 0.f;
    }
    wd_s[u] = wdv; sf_s[u] = sfv;
    if (l == 0) nx_s[g] = nexinv_g[pair];
  }
  f32x4 acc[4][6];
#pragma unroll
  for (int m = 0; m < 4; ++m)
#pragma unroll
    for (int n = 0; n < 6; ++n) acc[m][n] = (f32x4){0.f,0.f,0.f,0.f};
#pragma unroll 1
  for (int kc = 0; kc < 8; ++kc) {
    __syncthreads();
#pragma unroll
    for (int half = 0; half < 2; ++half) {
      uint4 vals[7];
#pragma unroll
      for (int j = 0; j < 7; ++j) {
        int u = (half*7 + j)*256 + tid;       // 0..3583
        const unsigned short* src;
        if (u < 512) { int row = u >> 3, k8 = u & 7; src = cb + (size_t)row*DIMD + kc*64 + k8*8; }
        else { int ub = u - 512; int row = ub >> 3, k8 = ub & 7; src = bb + (size_t)row*DIMD + kc*64 + k8*8; }
        vals[j] = *(const uint4*)src;
      }
#pragma unroll
      for (int j = 0; j < 7; ++j) {
        int u = (half*7 + j)*256 + tid;
        if (u < 512) { int row = u >> 3, k8 = u & 7; *(uint4*)&A_s[row*64 + (k8 ^ (row&7))*8] = vals[j]; }
        else { int ub = u - 512; int row = ub >> 3, k8 = ub & 7; *(uint4*)&B_s[row*64 + (k8 ^ (row&7))*8] = vals[j]; }
      }
    }
    __syncthreads();
#pragma unroll
    for (int ks = 0; ks < 2; ++ks) {
      int kh = 4*ks + (lane >> 4);
      bf16x8 af[4], bfr[6];
#pragma unroll
      for (int m = 0; m < 4; ++m) {
        int row = 16*m + (lane & 15);
        af[m] = *(const bf16x8*)&A_s[row*64 + (kh ^ (row&7))*8];
      }
#pragma unroll
      for (int n = 0; n < 6; ++n) {
        int row = 16*(6*wv + n) + (lane & 15);
        bfr[n] = *(const bf16x8*)&B_s[row*64 + (kh ^ (row&7))*8];
      }
#pragma unroll
      for (int m = 0; m < 4; ++m)
#pragma unroll
        for (int n = 0; n < 6; ++n)
          acc[m][n] = __builtin_amdgcn_mfma_f32_16x16x32_bf16(af[m], bfr[n], acc[m][n], 0, 0, 0);
    }
  }
  // fused epilogue: per wave, images g = 2*wv, 2*wv+1
  float pv[2] = {0.f, 0.f};
#pragma unroll
  for (int jj = 0; jj < 2; ++jj) {
    int g = 2*wv + jj;
    float nxi = nx_s[g];
#pragma unroll
    for (int m = 0; m < 4; ++m) {
      f32x4 ed = {0.f,0.f,0.f,0.f};
      f32x4 ms = {-FLT_MAX,-FLT_MAX,-FLT_MAX,-FLT_MAX};
#pragma unroll
      for (int j = 0; j < 3; ++j) {
        int l = 16*j + (lane & 15);
        float wdv = wd_s[g*48 + l];
        float sfv = sf_s[g*48 + l];
        f32x4 v = acc[m][3*jj + j];
#pragma unroll
        for (int q = 0; q < 4; ++q) {
          ed[q] += wdv * v[q];
          ms[q] = fmaxf(ms[q], (sfv > 0.5f) ? v[q] : -FLT_MAX);
        }
      }
#pragma unroll
      for (int sh = 1; sh < 16; sh <<= 1) {
#pragma unroll
        for (int q = 0; q < 4; ++q) {
          ed[q] += __shfl_xor(ed[q], sh, 64);
          ms[q] = fmaxf(ms[q], __shfl_xor(ms[q], sh, 64));
        }
      }
      // Only one lane per 16-lane group contributes (values are identical
      // across the group after the butterfly reduce).
      if ((lane & 15) == 0) {
#pragma unroll
        for (int q = 0; q < 4; ++q) {
          int r2 = 16*m + (lane >> 4)*4 + q;
          float smax = fmaxf(ms[q], ed[q]*nxi);
          pv[jj] += (r2 < len) ? smax : 0.f;
        }
      }
    }
    pv[jj] += __shfl_xor(pv[jj], 16, 64);
    pv[jj] += __shfl_xor(pv[jj], 32, 64);
  }
  if (lane == 0) {
#pragma unroll
    for (int jj = 0; jj < 2; ++jj) {
      int g = 2*wv + jj;
      out[(size_t)(btile*8 + g)*256 + i] = pv[jj] / (float)len;
    }
  }
}

extern "C" void kernel_launch(void* const* d_in, const int* in_sizes, int n_in,
                              void* d_out, int out_size, void* d_ws, size_t ws_size,
                              hipStream_t stream) {
  const float* img = (const float*)d_in[0];
  const float* cap = (const float*)d_in[1];
  const int* lens = (const int*)d_in[2];
  const float* lng = (const float*)d_in[3];
  const float* lnb = (const float*)d_in[4];
  const float* W1 = (const float*)d_in[5];
  const float* b1 = (const float*)d_in[6];
  const float* W2 = (const float*)d_in[7];
  const float* b2 = (const float*)d_in[8];
  const float* scale = (const float*)d_in[9];
  float* out = (float*)d_out;
  char* ws = (char*)d_ws;
  size_t off = 0;
  auto alloc = [&](size_t bytes) -> void* {
    void* p = ws + off;
    off += (bytes + 255) & ~(size_t)255;
    return p;
  };
  float* agn             = (float*)alloc((size_t)256*39*512*4);
  unsigned short* bm     = (unsigned short*)alloc((size_t)256*48*512*2);
  unsigned short* capn_bf = (unsigned short*)alloc((size_t)256*64*512*2);
  float* cglo    = (float*)alloc((size_t)256*512*4);
  float* gloraw  = (float*)alloc((size_t)256*512*4);
  float* na_g    = (float*)alloc((size_t)256*39*4);
  float* attSelf = (float*)alloc((size_t)256*39*4);
  float* G       = (float*)alloc((size_t)256*39*39*4);
  float* w1gT    = (float*)alloc((size_t)102*512*4);
  float* b1eff   = (float*)alloc((size_t)104*4);
  float* w2T     = (float*)alloc((size_t)39*104*4);
  float* wmat    = (float*)alloc((size_t)256*39*196*4);
  float* wdna_g  = (float*)alloc((size_t)65536*40*4);
  unsigned long long* selmask_g = (unsigned long long*)alloc((size_t)65536*8);
  float* nexinv_g = (float*)alloc((size_t)65536*4);
  (void)in_sizes; (void)n_in; (void)out_size; (void)ws_size;

  hipLaunchKernelGGL(k0_prep, dim3(64), dim3(256), 0, stream,
                     W1, b1, W2, lng, lnb, w1gT, b1eff, w2T);
  hipLaunchKernelGGL(k1a, dim3(256), dim3(256), 0, stream,
                     img, w1gT, b1eff, w2T, b2, scale, wmat);
  hipLaunchKernelGGL(k1agg, dim3(256), dim3(256), 0, stream,
                     img, wmat, agn, bm, na_g, gloraw);
  hipLaunchKernelGGL(k1b, dim3(256), dim3(256), 0, stream,
                     img, gloraw, agn, na_g, bm, attSelf, G);
  hipLaunchKernelGGL(k2, dim3(256), dim3(256), 0, stream,
                     cap, lens, capn_bf, cglo);
  hipLaunchKernelGGL(k3p, dim3(256, 4), dim3(256), 0, stream,
                     agn, cglo, attSelf, na_g, G, wdna_g, selmask_g, nexinv_g);
  hipLaunchKernelGGL(k3g, dim3(8192), dim3(256), 0, stream,
                     capn_bf, bm, wdna_g, selmask_g, nexinv_g, lens, out);
}